// Round 16
// baseline (30.349 us; speedup 1.0000x reference)
//
#include <hip/hip_runtime.h>
#include <hip/hip_bf16.h>

#define BLOCK 256
#define FBLOCK 1024
#define NXCD 8

typedef float v2f __attribute__((ext_vector_type(2)));
typedef float f4 __attribute__((ext_vector_type(4), aligned(4)));
typedef float f2 __attribute__((ext_vector_type(2), aligned(4)));

__device__ __forceinline__ v2f mkv2(float a, float b) { v2f r; r.x = a; r.y = b; return r; }

// per-component transcendentals (no packed variants exist)
__device__ __forceinline__ v2f vrcp(v2f x)  { return mkv2(__builtin_amdgcn_rcpf(x.x),  __builtin_amdgcn_rcpf(x.y)); }
__device__ __forceinline__ v2f vrsq(v2f x)  { return mkv2(__builtin_amdgcn_rsqf(x.x),  __builtin_amdgcn_rsqf(x.y)); }
__device__ __forceinline__ v2f vsqrtv(v2f x){ return mkv2(__builtin_amdgcn_sqrtf(x.x), __builtin_amdgcn_sqrtf(x.y)); }
__device__ __forceinline__ v2f vlogv(v2f x) { return mkv2(__logf(x.x), __logf(x.y)); }
__device__ __forceinline__ v2f vsinv(v2f x) { return mkv2(__sinf(x.x), __sinf(x.y)); }
__device__ __forceinline__ v2f vcosv(v2f x) { return mkv2(__cosf(x.x), __cosf(x.y)); }
__device__ __forceinline__ v2f vmaxv(v2f a, v2f b) { return mkv2(fmaxf(a.x,b.x), fmaxf(a.y,b.y)); }
__device__ __forceinline__ v2f vminv(v2f a, v2f b) { return mkv2(fminf(a.x,b.x), fminf(a.y,b.y)); }

// fast acos (A&S 4.4.45, ~6.7e-5 rad), elementwise on v2f
__device__ __forceinline__ v2f facosv(v2f x) {
    v2f ax = mkv2(fabsf(x.x), fabsf(x.y));
    v2f sq = vsqrtv(vmaxv((v2f)1.0f - ax, (v2f)0.0f));
    v2f poly = ((v2f)(-0.0187293f) * ax + (v2f)0.0742610f) * ax;
    poly = (poly - (v2f)0.2121144f) * ax + (v2f)1.5707288f;
    v2f ac = sq * poly;
    v2f res;
    res.x = (x.x < 0.0f) ? 3.14159274f - ac.x : ac.x;
    res.y = (x.y < 0.0f) ? 3.14159274f - ac.y : ac.y;
    return res;
}

// logm of TWO symmetric 3x3 SPD matrices at once: lane .x = D1, .y = D2.
// Branchless identical sequence -> packed v_pk_fma/mul/add_f32 dual fp32.
__device__ __forceinline__ void logm3v(const v2f m[6], v2f L[6]) {
    v2f a00 = m[0], a01 = m[1], a02 = m[2];
    v2f a11 = m[3], a12 = m[4], a22 = m[5];

    v2f q  = (a00 + a11 + a22) * (1.0f / 3.0f);
    v2f b00 = a00 - q, b11 = a11 - q, b22 = a22 - q;
    v2f p2 = b00*b00 + b11*b11 + b22*b22
           + 2.0f * (a01*a01 + a02*a02 + a12*a12);
    v2f u  = vmaxv(p2 * (1.0f / 6.0f), (v2f)1e-24f);
    v2f ip = vrsq(u);                   // 1/p
    v2f p  = u * ip;                    // p = sqrt(u)
    v2f detB = b00*(b11*b22 - a12*a12)
             - a01*(a01*b22 - a12*a02)
             + a02*(a01*a12 - b11*a02);
    v2f ip3 = ip * ip * ip;
    v2f r = vminv(vmaxv(0.5f * detB * ip3, (v2f)(-1.0f)), (v2f)1.0f);
    v2f phi = facosv(r) * (1.0f / 3.0f);
    v2f sph = vsinv(phi), cph = vcosv(phi);
    v2f whi = q + 2.0f * p * cph;
    v2f wlo = q - p * (cph + 1.7320508f * sph);
    v2f wmid = 3.0f * q - whi - wlo;
    v2f w0 = vmaxv(wlo, (v2f)1e-6f);    // eigenvalues >= 0.5 by construction
    v2f w1 = wmid;
    v2f w2 = whi;

    v2f l0 = vlogv(w0), l1 = vlogv(w1), l2 = vlogv(w2);
    v2f e = w2 * 1e-4f;
    v2f d01 = vmaxv(w1 - w0, e);
    v2f d12 = vmaxv(w2 - w1, e);
    v2f d02 = vmaxv(w2 - w0, e);
    v2f rP = vrcp(d01 * d12 * d02);               // single reciprocal each
    v2f dd01 = (l1 - l0) * (d12 * d02) * rP;      // (l1-l0)/d01
    v2f dd12 = (l2 - l1) * (d01 * d02) * rP;      // (l2-l1)/d12
    v2f dd012 = (dd12 - dd01) * (d01 * d12) * rP; // (dd12-dd01)/d02
    v2f k2 = dd012;
    v2f k1 = dd01 - dd012 * (w0 + w1);
    v2f k0 = l0 - dd01 * w0 + dd012 * (w0 * w1);

    v2f s00 = a00*a00 + a01*a01 + a02*a02;
    v2f s01 = a00*a01 + a01*a11 + a02*a12;
    v2f s02 = a00*a02 + a01*a12 + a02*a22;
    v2f s11 = a01*a01 + a11*a11 + a12*a12;
    v2f s12 = a01*a02 + a11*a12 + a12*a22;
    v2f s22 = a02*a02 + a12*a12 + a22*a22;

    L[0] = k0 + k1*a00 + k2*s00;
    L[1] =      k1*a01 + k2*s01;
    L[2] =      k1*a02 + k2*s02;
    L[3] = k0 + k1*a11 + k2*s11;
    L[4] =      k1*a12 + k2*s12;
    L[5] = k0 + k1*a22 + k2*s22;
}

// Vector loads: dwordx4 + dwordx2 + dword (3 VMEM instrs per matrix).
__device__ __forceinline__ void load6v(const float* __restrict__ base, int off9,
                                       float m[6]) {
    __builtin_assume(off9 >= 0);
    const float* p = base + off9;
    f4 v0 = *(const f4*)(p);        // floats 0..3 (float 3 unused, same line)
    f2 v1 = *(const f2*)(p + 4);    // floats 4,5
    float v2 = p[8];
    m[0] = v0.x; m[1] = v0.y; m[2] = v0.z;
    m[3] = v1.x; m[4] = v1.y; m[5] = v2;
}

__device__ __forceinline__ float distv(const v2f mv[6]) {
    v2f Lv[6];
    logm3v(const_cast<v2f*>(mv), Lv);
    float d0 = Lv[0].x - Lv[0].y, d1 = Lv[1].x - Lv[1].y;
    float d2 = Lv[2].x - Lv[2].y, d3 = Lv[3].x - Lv[3].y;
    float d4 = Lv[4].x - Lv[4].y, d5 = Lv[5].x - Lv[5].y;
    return d0*d0 + d3*d3 + d5*d5 + 2.0f * (d1*d1 + d2*d2 + d4*d4);
}

// Bijective XCD-chunked swizzle (m204): dispatch round-robins blocks over the
// 8 XCDs; this remap makes XCD k own one CONTIGUOUS chunk of the index space,
// restoring DRAM-page / L2-slice locality for the streamed arrays.
__device__ __forceinline__ int xcd_swizzle(int bid, int nwg) {
    int q = nwg >> 3, r = nwg & (NXCD - 1);
    int xcd = bid & (NXCD - 1);
    int o = bid >> 3;
    int base = (xcd < r) ? xcd * (q + 1) : r * (q + 1) + (xcd - r) * q;
    return base + o;
}

// Two pairs per thread, loads pinned above compute (R15 structure).
__global__ void __launch_bounds__(BLOCK)
le_partial(const float* __restrict__ D1, const float* __restrict__ D2,
           float* __restrict__ partial, int n, int npass) {
    const int tid = threadIdx.x;
    const int T = (int)gridDim.x * BLOCK;
    const int wg = xcd_swizzle((int)blockIdx.x, (int)gridDim.x);
    float acc = 0.0f;

    int i = wg * BLOCK + tid;
    #pragma unroll 1
    for (int pass = 0; pass < npass; ++pass, i += 2 * T) {  // npass==1 normally
        int ia = i;
        int ib = i + T;
        bool ha = (ia < n);
        bool hb = (ib < n);
        int iac = ha ? ia : 0;
        int ibc = hb ? ib : 0;

        float m1a[6], m2a[6], m1b[6], m2b[6];
        load6v(D1, 9 * iac, m1a);
        load6v(D2, 9 * iac, m2a);
        load6v(D1, 9 * ibc, m1b);
        load6v(D2, 9 * ibc, m2b);
        __builtin_amdgcn_sched_barrier(0);   // pin loads above compute

        v2f mva[6], mvb[6];
        #pragma unroll
        for (int j = 0; j < 6; ++j) {
            mva[j] = mkv2(m1a[j], m2a[j]);
            mvb[j] = mkv2(m1b[j], m2b[j]);
        }
        float da = distv(mva);
        float db = distv(mvb);
        acc += (ha ? da : 0.0f) + (hb ? db : 0.0f);
    }

    // wave reduce (wave = 64)
    #pragma unroll
    for (int off = 32; off > 0; off >>= 1)
        acc += __shfl_down(acc, off, 64);
    __shared__ float wsum[BLOCK / 64];
    if ((tid & 63) == 0) wsum[tid >> 6] = acc;
    __syncthreads();
    if (tid == 0) {
        float s = 0.0f;
        #pragma unroll
        for (int j = 0; j < BLOCK / 64; ++j) s += wsum[j];
        partial[blockIdx.x] = s;    // index by raw blockIdx: still one slot each
    }
}

__global__ void __launch_bounds__(FBLOCK)
le_final(const float* __restrict__ partial, int nparts,
         float* __restrict__ out, double invN) {
    double s = 0.0;
    for (int i = threadIdx.x; i < nparts; i += FBLOCK)
        s += (double)partial[i];
    #pragma unroll
    for (int off = 32; off > 0; off >>= 1)
        s += __shfl_down(s, off, 64);
    __shared__ double ws[FBLOCK / 64];
    if ((threadIdx.x & 63) == 0) ws[threadIdx.x >> 6] = s;
    __syncthreads();
    if (threadIdx.x == 0) {
        double t = 0.0;
        #pragma unroll
        for (int i = 0; i < FBLOCK / 64; ++i) t += ws[i];
        out[0] = (float)(t * invN);
    }
}

extern "C" void kernel_launch(void* const* d_in, const int* in_sizes, int n_in,
                              void* d_out, int out_size, void* d_ws, size_t ws_size,
                              hipStream_t stream) {
    const float* D1 = (const float*)d_in[0];
    const float* D2 = (const float*)d_in[1];
    float* out = (float*)d_out;
    float* partial = (float*)d_ws;

    int n = in_sizes[0] / 9;
    int nblk2 = (n + 2 * BLOCK - 1) / (2 * BLOCK);   // two pairs per thread

    int grid = nblk2;
    int maxblocks = (int)(ws_size / sizeof(float));
    if (maxblocks > 0 && grid > maxblocks) grid = maxblocks;  // ws guard
    if (grid < 1) grid = 1;
    int npass = (nblk2 + grid - 1) / grid;            // ==1 unless ws-capped

    le_partial<<<grid, BLOCK, 0, stream>>>(D1, D2, partial, n, npass);
    le_final<<<1, FBLOCK, 0, stream>>>(partial, grid, out, 1.0 / (double)n);
}

// Round 17
// 29.920 us; speedup vs baseline: 1.0144x; 1.0144x over previous
//
#include <hip/hip_runtime.h>
#include <hip/hip_bf16.h>

#define BLOCK 256
#define FBLOCK 1024

typedef float v2f __attribute__((ext_vector_type(2)));
typedef float f4 __attribute__((ext_vector_type(4), aligned(4)));
typedef float f2 __attribute__((ext_vector_type(2), aligned(4)));

__device__ __forceinline__ v2f mkv2(float a, float b) { v2f r; r.x = a; r.y = b; return r; }

// per-component transcendentals (no packed variants exist)
__device__ __forceinline__ v2f vrcp(v2f x)  { return mkv2(__builtin_amdgcn_rcpf(x.x),  __builtin_amdgcn_rcpf(x.y)); }
__device__ __forceinline__ v2f vrsq(v2f x)  { return mkv2(__builtin_amdgcn_rsqf(x.x),  __builtin_amdgcn_rsqf(x.y)); }
__device__ __forceinline__ v2f vsqrtv(v2f x){ return mkv2(__builtin_amdgcn_sqrtf(x.x), __builtin_amdgcn_sqrtf(x.y)); }
__device__ __forceinline__ v2f vlogv(v2f x) { return mkv2(__logf(x.x), __logf(x.y)); }
__device__ __forceinline__ v2f vsinv(v2f x) { return mkv2(__sinf(x.x), __sinf(x.y)); }
__device__ __forceinline__ v2f vcosv(v2f x) { return mkv2(__cosf(x.x), __cosf(x.y)); }
__device__ __forceinline__ v2f vmaxv(v2f a, v2f b) { return mkv2(fmaxf(a.x,b.x), fmaxf(a.y,b.y)); }
__device__ __forceinline__ v2f vminv(v2f a, v2f b) { return mkv2(fminf(a.x,b.x), fminf(a.y,b.y)); }

// fast acos (A&S 4.4.45, ~6.7e-5 rad), elementwise on v2f
__device__ __forceinline__ v2f facosv(v2f x) {
    v2f ax = mkv2(fabsf(x.x), fabsf(x.y));
    v2f sq = vsqrtv(vmaxv((v2f)1.0f - ax, (v2f)0.0f));
    v2f poly = ((v2f)(-0.0187293f) * ax + (v2f)0.0742610f) * ax;
    poly = (poly - (v2f)0.2121144f) * ax + (v2f)1.5707288f;
    v2f ac = sq * poly;
    v2f res;
    res.x = (x.x < 0.0f) ? 3.14159274f - ac.x : ac.x;
    res.y = (x.y < 0.0f) ? 3.14159274f - ac.y : ac.y;
    return res;
}

// logm of TWO symmetric 3x3 SPD matrices at once: lane .x = D1, .y = D2.
// Branchless identical sequence -> packed v_pk_fma/mul/add_f32 dual fp32.
__device__ __forceinline__ void logm3v(const v2f m[6], v2f L[6]) {
    v2f a00 = m[0], a01 = m[1], a02 = m[2];
    v2f a11 = m[3], a12 = m[4], a22 = m[5];

    v2f q  = (a00 + a11 + a22) * (1.0f / 3.0f);
    v2f b00 = a00 - q, b11 = a11 - q, b22 = a22 - q;
    v2f p2 = b00*b00 + b11*b11 + b22*b22
           + 2.0f * (a01*a01 + a02*a02 + a12*a12);
    v2f u  = vmaxv(p2 * (1.0f / 6.0f), (v2f)1e-24f);
    v2f ip = vrsq(u);                   // 1/p
    v2f p  = u * ip;                    // p = sqrt(u)
    v2f detB = b00*(b11*b22 - a12*a12)
             - a01*(a01*b22 - a12*a02)
             + a02*(a01*a12 - b11*a02);
    v2f ip3 = ip * ip * ip;
    v2f r = vminv(vmaxv(0.5f * detB * ip3, (v2f)(-1.0f)), (v2f)1.0f);
    v2f phi = facosv(r) * (1.0f / 3.0f);
    v2f sph = vsinv(phi), cph = vcosv(phi);
    v2f whi = q + 2.0f * p * cph;
    v2f wlo = q - p * (cph + 1.7320508f * sph);
    v2f wmid = 3.0f * q - whi - wlo;
    v2f w0 = vmaxv(wlo, (v2f)1e-6f);    // eigenvalues >= 0.5 by construction
    v2f w1 = wmid;
    v2f w2 = whi;

    v2f l0 = vlogv(w0), l1 = vlogv(w1), l2 = vlogv(w2);
    v2f e = w2 * 1e-4f;
    v2f d01 = vmaxv(w1 - w0, e);
    v2f d12 = vmaxv(w2 - w1, e);
    v2f d02 = vmaxv(w2 - w0, e);
    v2f rP = vrcp(d01 * d12 * d02);               // single reciprocal each
    v2f dd01 = (l1 - l0) * (d12 * d02) * rP;      // (l1-l0)/d01
    v2f dd12 = (l2 - l1) * (d01 * d02) * rP;      // (l2-l1)/d12
    v2f dd012 = (dd12 - dd01) * (d01 * d12) * rP; // (dd12-dd01)/d02
    v2f k2 = dd012;
    v2f k1 = dd01 - dd012 * (w0 + w1);
    v2f k0 = l0 - dd01 * w0 + dd012 * (w0 * w1);

    v2f s00 = a00*a00 + a01*a01 + a02*a02;
    v2f s01 = a00*a01 + a01*a11 + a02*a12;
    v2f s02 = a00*a02 + a01*a12 + a02*a22;
    v2f s11 = a01*a01 + a11*a11 + a12*a12;
    v2f s12 = a01*a02 + a11*a12 + a12*a22;
    v2f s22 = a02*a02 + a12*a12 + a22*a22;

    L[0] = k0 + k1*a00 + k2*s00;
    L[1] =      k1*a01 + k2*s01;
    L[2] =      k1*a02 + k2*s02;
    L[3] = k0 + k1*a11 + k2*s11;
    L[4] =      k1*a12 + k2*s12;
    L[5] = k0 + k1*a22 + k2*s22;
}

// Vector loads: dwordx4 + dwordx2 + dword (3 VMEM instrs per matrix).
__device__ __forceinline__ void load6v(const float* __restrict__ base, int off9,
                                       float m[6]) {
    __builtin_assume(off9 >= 0);
    const float* p = base + off9;
    f4 v0 = *(const f4*)(p);        // floats 0..3 (float 3 unused, same line)
    f2 v1 = *(const f2*)(p + 4);    // floats 4,5
    float v2 = p[8];
    m[0] = v0.x; m[1] = v0.y; m[2] = v0.z;
    m[3] = v1.x; m[4] = v1.y; m[5] = v2;
}

__device__ __forceinline__ float distv(const v2f mv[6]) {
    v2f Lv[6];
    logm3v(const_cast<v2f*>(mv), Lv);
    float d0 = Lv[0].x - Lv[0].y, d1 = Lv[1].x - Lv[1].y;
    float d2 = Lv[2].x - Lv[2].y, d3 = Lv[3].x - Lv[3].y;
    float d4 = Lv[4].x - Lv[4].y, d5 = Lv[5].x - Lv[5].y;
    return d0*d0 + d3*d3 + d5*d5 + 2.0f * (d1*d1 + d2*d2 + d4*d4);
}

// Two pairs per thread: all 12 loads issued up front and PINNED above the
// compute with sched_barrier(0). Pair B's memory latency hides under pair A's
// ~500-cycle compute; two independent packed chains interleave on the VALU.
__global__ void __launch_bounds__(BLOCK)
le_partial(const float* __restrict__ D1, const float* __restrict__ D2,
           float* __restrict__ partial, int n, int npass) {
    const int tid = threadIdx.x;
    const int T = (int)gridDim.x * BLOCK;
    float acc = 0.0f;

    int i = (int)blockIdx.x * BLOCK + tid;
    #pragma unroll 1
    for (int pass = 0; pass < npass; ++pass, i += 2 * T) {  // npass==1 normally
        int ia = i;
        int ib = i + T;
        bool ha = (ia < n);
        bool hb = (ib < n);
        int iac = ha ? ia : 0;
        int ibc = hb ? ib : 0;

        float m1a[6], m2a[6], m1b[6], m2b[6];
        load6v(D1, 9 * iac, m1a);
        load6v(D2, 9 * iac, m2a);
        load6v(D1, 9 * ibc, m1b);
        load6v(D2, 9 * ibc, m2b);
        __builtin_amdgcn_sched_barrier(0);   // pin loads above compute

        v2f mva[6], mvb[6];
        #pragma unroll
        for (int j = 0; j < 6; ++j) {
            mva[j] = mkv2(m1a[j], m2a[j]);
            mvb[j] = mkv2(m1b[j], m2b[j]);
        }
        float da = distv(mva);
        float db = distv(mvb);
        acc += (ha ? da : 0.0f) + (hb ? db : 0.0f);
    }

    // wave reduce (wave = 64)
    #pragma unroll
    for (int off = 32; off > 0; off >>= 1)
        acc += __shfl_down(acc, off, 64);
    __shared__ float wsum[BLOCK / 64];
    if ((tid & 63) == 0) wsum[tid >> 6] = acc;
    __syncthreads();
    if (tid == 0) {
        float s = 0.0f;
        #pragma unroll
        for (int j = 0; j < BLOCK / 64; ++j) s += wsum[j];
        partial[blockIdx.x] = s;
    }
}

__global__ void __launch_bounds__(FBLOCK)
le_final(const float* __restrict__ partial, int nparts,
         float* __restrict__ out, double invN) {
    double s = 0.0;
    for (int i = threadIdx.x; i < nparts; i += FBLOCK)
        s += (double)partial[i];
    #pragma unroll
    for (int off = 32; off > 0; off >>= 1)
        s += __shfl_down(s, off, 64);
    __shared__ double ws[FBLOCK / 64];
    if ((threadIdx.x & 63) == 0) ws[threadIdx.x >> 6] = s;
    __syncthreads();
    if (threadIdx.x == 0) {
        double t = 0.0;
        #pragma unroll
        for (int i = 0; i < FBLOCK / 64; ++i) t += ws[i];
        out[0] = (float)(t * invN);
    }
}

extern "C" void kernel_launch(void* const* d_in, const int* in_sizes, int n_in,
                              void* d_out, int out_size, void* d_ws, size_t ws_size,
                              hipStream_t stream) {
    const float* D1 = (const float*)d_in[0];
    const float* D2 = (const float*)d_in[1];
    float* out = (float*)d_out;
    float* partial = (float*)d_ws;

    int n = in_sizes[0] / 9;
    int nblk2 = (n + 2 * BLOCK - 1) / (2 * BLOCK);   // two pairs per thread

    int grid = nblk2;
    int maxblocks = (int)(ws_size / sizeof(float));
    if (maxblocks > 0 && grid > maxblocks) grid = maxblocks;  // ws guard
    if (grid < 1) grid = 1;
    int npass = (nblk2 + grid - 1) / grid;            // ==1 unless ws-capped

    le_partial<<<grid, BLOCK, 0, stream>>>(D1, D2, partial, n, npass);
    le_final<<<1, FBLOCK, 0, stream>>>(partial, grid, out, 1.0 / (double)n);
}